// Round 3
// baseline (130.170 us; speedup 1.0000x reference)
//
#include <hip/hip_runtime.h>
#include <hip/hip_bf16.h>

typedef __bf16 bf16x8 __attribute__((ext_vector_type(8)));
typedef float f32x4 __attribute__((ext_vector_type(4)));

#define N_NODE 50000
#define KPATH 8
#define LPATH 6
#define DNODE 64
#define DPATH 128
#define KDIM 320                 // DNODE*(LPATH-1)
#define NPAIR (N_NODE * KPATH)   // 400000
#define M_BLK 32
#define NBLK (NPAIR / M_BLK)     // 12500
#define ROW_BYTES 640            // 320 bf16, unpadded; swizzle fixes conflicts
#define WF_BYTES 81920
#define FEATB_BYTES (N_NODE * DNODE * 2)

// XOR-swizzle: 16B unit moved within its 128B group by row. 640 = 5*128 so
// the XOR (max 112) never crosses a row boundary.
__device__ __forceinline__ int swz(int row, int bytecol) {
    return row * ROW_BYTES + (bytecol ^ ((row & 7) << 4));
}

// Pre-swizzle W (DPATH x KDIM, row-major f32) into bf16 MFMA B-fragment order:
// wf[((nt*10+ks)*64+lane)*8+j] = W[n=nt*16+(lane&15)][k=ks*32+(lane>>4)*8+j]
__global__ void wfrag_prep(const float* __restrict__ W, __bf16* __restrict__ wf) {
    int t = blockIdx.x * 256 + threadIdx.x;
    if (t >= 8 * 10 * 64 * 8) return;
    int j    = t & 7;
    int lane = (t >> 3) & 63;
    int ks   = (t >> 9) % 10;
    int nt   = t / 5120;
    int k = ks * 32 + (lane >> 4) * 8 + j;
    int n = nt * 16 + (lane & 15);
    wf[t] = (__bf16)W[n * KDIM + k];
}

// feat f32 -> bf16 (each thread converts 8 elements)
__global__ void feat_prep(const float* __restrict__ f, __bf16* __restrict__ fb) {
    int t = blockIdx.x * 256 + threadIdx.x;
    if (t >= N_NODE * DNODE / 8) return;
    float4 a = ((const float4*)f)[t * 2];
    float4 b = ((const float4*)f)[t * 2 + 1];
    union { bf16x8 v; __bf16 e[8]; } u;
    u.e[0] = (__bf16)a.x; u.e[1] = (__bf16)a.y; u.e[2] = (__bf16)a.z; u.e[3] = (__bf16)a.w;
    u.e[4] = (__bf16)b.x; u.e[5] = (__bf16)b.y; u.e[6] = (__bf16)b.z; u.e[7] = (__bf16)b.w;
    ((bf16x8*)fb)[t] = u.v;
}

template <bool BF16FEAT>
__global__ __launch_bounds__(256) void path_gemm(
    const void*  __restrict__ featv,
    const float* __restrict__ weight,
    const int*   __restrict__ paths,
    const int*   __restrict__ eids,
    const __bf16* __restrict__ wf,
    float* __restrict__ out)
{
    __shared__ bf16x8 AsVec[M_BLK * ROW_BYTES / 16];   // 20,480 B -> 8 blocks/CU
    char* asb = (char*)AsVec;

    const int  t  = threadIdx.x;
    const long p0 = (long)blockIdx.x * M_BLK;

    // ---------------- stage A tile: gather + combine -> bf16 LDS ----------
    {
        const int  r  = t >> 3;          // row 0..31
        const int  s  = t & 7;           // 8-dim (16B) slice
        const int  d0 = s * 8;
        const long p  = p0 + r;
        const int* pp = paths + p * LPATH;
        const int* ee = eids  + p * (LPATH - 1);

        int idx[LPATH];
#pragma unroll
        for (int l = 0; l < LPATH; ++l) idx[l] = pp[l];
        float ew[LPATH - 1];
#pragma unroll
        for (int l = 0; l < LPATH - 1; ++l) ew[l] = weight[ee[l]];

        float x[8];
#pragma unroll
        for (int l = 0; l < LPATH; ++l) {
            float y[8];
            const int id = idx[l];
            if (id >= N_NODE) {
#pragma unroll
                for (int i = 0; i < 8; ++i) y[i] = 0.f;
            } else if (BF16FEAT) {
                union { bf16x8 v; __bf16 e[8]; } u;
                u.v = *(const bf16x8*)((const __bf16*)featv + (long)id * DNODE + d0);
#pragma unroll
                for (int i = 0; i < 8; ++i) y[i] = (float)u.e[i];
            } else {
                const float4* sp = (const float4*)((const float*)featv + (long)id * DNODE + d0);
                *(float4*)&y[0] = sp[0];
                *(float4*)&y[4] = sp[1];
            }
            if (l > 0) {
                union { bf16x8 v; __bf16 e[8]; } u;
#pragma unroll
                for (int i = 0; i < 8; ++i) u.e[i] = (__bf16)(x[i] + ew[l - 1] * y[i]);
                *(bf16x8*)(asb + swz(r, (l - 1) * 128 + s * 16)) = u.v;
            }
#pragma unroll
            for (int i = 0; i < 8; ++i) x[i] = y[i];
        }
    }
    __syncthreads();

    // ---------------- MFMA: each wave computes 32 rows x 32 cols ----------
    const int wave = t >> 6;
    const int lane = t & 63;
    const int lrow = lane & 15;
    const int h    = lane >> 4;

    f32x4 acc[2][2];
#pragma unroll
    for (int mt = 0; mt < 2; ++mt)
#pragma unroll
        for (int nt = 0; nt < 2; ++nt)
            acc[mt][nt] = (f32x4){0.f, 0.f, 0.f, 0.f};

#pragma unroll
    for (int ks = 0; ks < 10; ++ks) {
        bf16x8 b0 = *(const bf16x8*)(wf + (((wave * 2 + 0) * 10 + ks) * 64 + lane) * 8);
        bf16x8 b1 = *(const bf16x8*)(wf + (((wave * 2 + 1) * 10 + ks) * 64 + lane) * 8);
#pragma unroll
        for (int mt = 0; mt < 2; ++mt) {
            bf16x8 a = *(const bf16x8*)(asb + swz(mt * 16 + lrow, ks * 64 + h * 16));
            acc[mt][0] = __builtin_amdgcn_mfma_f32_16x16x32_bf16(a, b0, acc[mt][0], 0, 0, 0);
            acc[mt][1] = __builtin_amdgcn_mfma_f32_16x16x32_bf16(a, b1, acc[mt][1], 0, 0, 0);
        }
    }

    // ---------------- epilogue: C[row=(lane>>4)*4+q][col=lane&15] ---------
    const int rbase = h * 4;
#pragma unroll
    for (int mt = 0; mt < 2; ++mt) {
#pragma unroll
        for (int nt = 0; nt < 2; ++nt) {
#pragma unroll
            for (int q = 0; q < 4; ++q) {
                long row = p0 + mt * 16 + rbase + q;
                int  col = wave * 32 + nt * 16 + lrow;
                out[row * DPATH + col] = acc[mt][nt][q];
            }
        }
    }
}

extern "C" void kernel_launch(void* const* d_in, const int* in_sizes, int n_in,
                              void* d_out, int out_size, void* d_ws, size_t ws_size,
                              hipStream_t stream) {
    const float* feat   = (const float*)d_in[0];
    const float* weight = (const float*)d_in[1];
    const float* W      = (const float*)d_in[2];
    const int*   paths  = (const int*)d_in[3];
    const int*   eids   = (const int*)d_in[4];
    float* out = (float*)d_out;
    __bf16* wf = (__bf16*)d_ws;                                  // 81,920 B
    __bf16* featb = (__bf16*)((char*)d_ws + WF_BYTES);           // 6,400,000 B

    wfrag_prep<<<160, 256, 0, stream>>>(W, wf);

    if (ws_size >= (size_t)WF_BYTES + FEATB_BYTES) {
        feat_prep<<<(N_NODE * DNODE / 8 + 255) / 256, 256, 0, stream>>>(feat, featb);
        path_gemm<true><<<NBLK, 256, 0, stream>>>(featb, weight, paths, eids, wf, out);
    } else {
        path_gemm<false><<<NBLK, 256, 0, stream>>>(feat, weight, paths, eids, wf, out);
    }
}

// Round 4
// 123.618 us; speedup vs baseline: 1.0530x; 1.0530x over previous
//
#include <hip/hip_runtime.h>
#include <hip/hip_bf16.h>

typedef __bf16 bf16x8 __attribute__((ext_vector_type(8)));
typedef float f32x4 __attribute__((ext_vector_type(4)));

#define N_NODE 50000
#define KPATH 8
#define LPATH 6
#define DNODE 64
#define DPATH 128
#define KDIM 320                 // DNODE*(LPATH-1)
#define NPAIR (N_NODE * KPATH)   // 400000
#define M_BLK 32
#define NBLK (NPAIR / M_BLK)     // 12500
#define ROW_BYTES 640            // 320 bf16, unpadded; swizzle fixes conflicts
#define WF_BYTES 81920
#define FEATB_BYTES (N_NODE * DNODE * 2)

// XOR-swizzle: 16B unit moved within its 128B group by row. 640 = 5*128 so
// the XOR (max 112) never crosses a row boundary.
__device__ __forceinline__ int swz(int row, int bytecol) {
    return row * ROW_BYTES + (bytecol ^ ((row & 7) << 4));
}

// Pre-swizzle W (DPATH x KDIM, row-major f32) into bf16 MFMA B-fragment order:
// wf[((nt*10+ks)*64+lane)*8+j] = W[n=nt*16+(lane&15)][k=ks*32+(lane>>4)*8+j]
__global__ void wfrag_prep(const float* __restrict__ W, __bf16* __restrict__ wf) {
    int t = blockIdx.x * 256 + threadIdx.x;
    if (t >= 8 * 10 * 64 * 8) return;
    int j    = t & 7;
    int lane = (t >> 3) & 63;
    int ks   = (t >> 9) % 10;
    int nt   = t / 5120;
    int k = ks * 32 + (lane >> 4) * 8 + j;
    int n = nt * 16 + (lane & 15);
    wf[t] = (__bf16)W[n * KDIM + k];
}

// feat f32 -> bf16 (each thread converts 8 elements)
__global__ void feat_prep(const float* __restrict__ f, __bf16* __restrict__ fb) {
    int t = blockIdx.x * 256 + threadIdx.x;
    if (t >= N_NODE * DNODE / 8) return;
    float4 a = ((const float4*)f)[t * 2];
    float4 b = ((const float4*)f)[t * 2 + 1];
    union { bf16x8 v; __bf16 e[8]; } u;
    u.e[0] = (__bf16)a.x; u.e[1] = (__bf16)a.y; u.e[2] = (__bf16)a.z; u.e[3] = (__bf16)a.w;
    u.e[4] = (__bf16)b.x; u.e[5] = (__bf16)b.y; u.e[6] = (__bf16)b.z; u.e[7] = (__bf16)b.w;
    ((bf16x8*)fb)[t] = u.v;
}

template <bool BF16FEAT>
__global__ __launch_bounds__(256) void path_gemm(
    const void*  __restrict__ featv,
    const float* __restrict__ weight,
    const int*   __restrict__ paths,
    const int*   __restrict__ eids,
    const __bf16* __restrict__ wf,
    float* __restrict__ out)
{
    __shared__ bf16x8 AsVec[M_BLK * ROW_BYTES / 16];   // 20,480 B -> 8 blocks/CU
    char* asb = (char*)AsVec;

    const int  t  = threadIdx.x;
    const long p0 = (long)blockIdx.x * M_BLK;

    // ---------------- stage A tile: gather + combine -> bf16 LDS ----------
    {
        const int  r  = t >> 3;          // row 0..31
        const int  s  = t & 7;           // 8-dim (16B) slice
        const int  d0 = s * 8;
        const int  lr = r & 7;           // row-local index within this wave
        const long p  = p0 + r;

        // Lane-split scalar gathers: lane s<6 loads path idx s, lane s<5
        // loads edge id s + its weight; broadcast to the row's 8 lanes.
        int pv = 0;
        if (s < LPATH) pv = __builtin_nontemporal_load(paths + p * LPATH + s);
        float wv = 0.f;
        if (s < LPATH - 1) {
            int ev = __builtin_nontemporal_load(eids + p * (LPATH - 1) + s);
            wv = weight[ev];
        }

        int idx[LPATH];
#pragma unroll
        for (int l = 0; l < LPATH; ++l) idx[l] = __shfl(pv, lr * 8 + l, 64);
        float ew[LPATH - 1];
#pragma unroll
        for (int l = 0; l < LPATH - 1; ++l) ew[l] = __shfl(wv, lr * 8 + l, 64);

        float x[8];
#pragma unroll
        for (int l = 0; l < LPATH; ++l) {
            float y[8];
            const int id = idx[l];
            if (id >= N_NODE) {
#pragma unroll
                for (int i = 0; i < 8; ++i) y[i] = 0.f;
            } else if (BF16FEAT) {
                union { bf16x8 v; __bf16 e[8]; } u;
                u.v = *(const bf16x8*)((const __bf16*)featv + (long)id * DNODE + d0);
#pragma unroll
                for (int i = 0; i < 8; ++i) y[i] = (float)u.e[i];
            } else {
                const float4* sp = (const float4*)((const float*)featv + (long)id * DNODE + d0);
                *(float4*)&y[0] = sp[0];
                *(float4*)&y[4] = sp[1];
            }
            if (l > 0) {
                union { bf16x8 v; __bf16 e[8]; } u;
#pragma unroll
                for (int i = 0; i < 8; ++i) u.e[i] = (__bf16)(x[i] + ew[l - 1] * y[i]);
                *(bf16x8*)(asb + swz(r, (l - 1) * 128 + s * 16)) = u.v;
            }
#pragma unroll
            for (int i = 0; i < 8; ++i) x[i] = y[i];
        }
    }
    __syncthreads();

    // ---------------- MFMA: each wave computes 32 rows x 32 cols ----------
    const int wave = t >> 6;
    const int lane = t & 63;
    const int lrow = lane & 15;
    const int h    = lane >> 4;

    f32x4 acc[2][2];
#pragma unroll
    for (int mt = 0; mt < 2; ++mt)
#pragma unroll
        for (int nt = 0; nt < 2; ++nt)
            acc[mt][nt] = (f32x4){0.f, 0.f, 0.f, 0.f};

#pragma unroll
    for (int ks = 0; ks < 10; ++ks) {
        bf16x8 b0 = *(const bf16x8*)(wf + (((wave * 2 + 0) * 10 + ks) * 64 + lane) * 8);
        bf16x8 b1 = *(const bf16x8*)(wf + (((wave * 2 + 1) * 10 + ks) * 64 + lane) * 8);
#pragma unroll
        for (int mt = 0; mt < 2; ++mt) {
            bf16x8 a = *(const bf16x8*)(asb + swz(mt * 16 + lrow, ks * 64 + h * 16));
            acc[mt][0] = __builtin_amdgcn_mfma_f32_16x16x32_bf16(a, b0, acc[mt][0], 0, 0, 0);
            acc[mt][1] = __builtin_amdgcn_mfma_f32_16x16x32_bf16(a, b1, acc[mt][1], 0, 0, 0);
        }
    }

    // ---------------- epilogue: non-temporal stores (don't thrash L2/L3) --
    const int rbase = h * 4;
#pragma unroll
    for (int mt = 0; mt < 2; ++mt) {
#pragma unroll
        for (int nt = 0; nt < 2; ++nt) {
#pragma unroll
            for (int q = 0; q < 4; ++q) {
                long row = p0 + mt * 16 + rbase + q;
                int  col = wave * 32 + nt * 16 + lrow;
                __builtin_nontemporal_store(acc[mt][nt][q], &out[row * DPATH + col]);
            }
        }
    }
}

extern "C" void kernel_launch(void* const* d_in, const int* in_sizes, int n_in,
                              void* d_out, int out_size, void* d_ws, size_t ws_size,
                              hipStream_t stream) {
    const float* feat   = (const float*)d_in[0];
    const float* weight = (const float*)d_in[1];
    const float* W      = (const float*)d_in[2];
    const int*   paths  = (const int*)d_in[3];
    const int*   eids   = (const int*)d_in[4];
    float* out = (float*)d_out;
    __bf16* wf = (__bf16*)d_ws;                                  // 81,920 B
    __bf16* featb = (__bf16*)((char*)d_ws + WF_BYTES);           // 6,400,000 B

    wfrag_prep<<<160, 256, 0, stream>>>(W, wf);

    if (ws_size >= (size_t)WF_BYTES + FEATB_BYTES) {
        feat_prep<<<(N_NODE * DNODE / 8 + 255) / 256, 256, 0, stream>>>(feat, featb);
        path_gemm<true><<<NBLK, 256, 0, stream>>>(featb, weight, paths, eids, wf, out);
    } else {
        path_gemm<false><<<NBLK, 256, 0, stream>>>(feat, weight, paths, eids, wf, out);
    }
}